// Round 3
// baseline (224.317 us; speedup 1.0000x reference)
//
#include <hip/hip_runtime.h>
#include <hip/hip_bf16.h>
#include <math.h>

// Attention_10840497455414: x[8,1024,768] fp32 -> QKV -> 12-head attention ->
// proj+bias -> fp32 out. Compute in bf16 MFMA (16x16x32), fp32 accumulation.
//
// Pipeline (intermediates bf16 in d_ws). 4 launches:
//   0) convert3  : one kernel converts x, w_qkv, w_proj fp32->bf16
//   1) qkv_gemm  : [8192,768] x [2304,768]^T -> Q(scaled by 1/8*log2e)/K/Vt
//                  LDS-transposed coalesced epilogue; V emitted as Vt directly.
//                  launch_bounds(256,4). R11 lesson: (256,5) crashed the
//                  harness — VGPR_Count=60 is ArchVGPRs only; +64 AGPRs for
//                  acc[4][4] = ~124 regs/wave > 512/5 budget. Do NOT raise.
//   2) attn v7   : R12 — T14 async-STAGE split (m214 attn +17%): K/V tiles
//                  are reg-staged (global->reg issued during PREVIOUS tile's
//                  compute), written to LDS via ds_write after a raw
//                  s_barrier. Raw barriers + counted waits replace
//                  __syncthreads (whose compiler-emitted vmcnt(0) drain would
//                  serialize the prefetch). T5 setprio around MFMA clusters
//                  (m191 attn +4-7%). Numerics identical to v6.
//   3) proj_gemm : M128xN128 reusing gemm_tile_768 -> grid (6,64)=384 blocks.

typedef unsigned short u16;
typedef __attribute__((ext_vector_type(8))) short bf16x8;   // 8 bf16 = 4 VGPRs
typedef __attribute__((ext_vector_type(4))) float f32x4;    // MFMA C/D
typedef __attribute__((ext_vector_type(4))) unsigned int u32x4;

#define MFMA_BF16(a, b, c) __builtin_amdgcn_mfma_f32_16x16x32_bf16((a), (b), (c), 0, 0, 0)

static __device__ __forceinline__ void gld_lds16(const void* g, void* l) {
  __builtin_amdgcn_global_load_lds(
      (__attribute__((address_space(1))) void*)(g),
      (__attribute__((address_space(3))) void*)(l), 16, 0, 0);
}

static __device__ __forceinline__ u16 f2bf(float f) {
  __hip_bfloat16 h = __float2bfloat16(f);
  return *(u16*)&h;
}

static __device__ __forceinline__ float fast_exp2(float x) {
#if __has_builtin(__builtin_amdgcn_exp2f)
  return __builtin_amdgcn_exp2f(x);   // raw v_exp_f32 (D = 2^S0)
#else
  return exp2f(x);
#endif
}

// fp32 -> bf16 (RNE), non-finite sanitized to 0. 4 elems per thread.
static __device__ __forceinline__ void conv4(const float* src, u16* dst, int i) {
  const float4 v = *(const float4*)(src + i);
  float f0 = v.x, f1 = v.y, f2 = v.z, f3 = v.w;
  if (!isfinite(f0)) f0 = 0.f;
  if (!isfinite(f1)) f1 = 0.f;
  if (!isfinite(f2)) f2 = 0.f;
  if (!isfinite(f3)) f3 = 0.f;
  ushort4 o;
  o.x = f2bf(f0); o.y = f2bf(f1); o.z = f2bf(f2); o.w = f2bf(f3);
  *(ushort4*)(dst + i) = o;
}

// one launch for all three conversions (x: 6144 blocks, wq: 1728, wp: 576)
__global__ __launch_bounds__(256) void convert3_kernel(
    const float* __restrict__ x,  u16* __restrict__ xb,
    const float* __restrict__ wq, u16* __restrict__ wqb,
    const float* __restrict__ wp, u16* __restrict__ wpb)
{
  const int blk = blockIdx.x;
  if (blk < 6144)      conv4(x,  xb,  (blk * 256 + threadIdx.x) * 4);
  else if (blk < 7872) conv4(wq, wqb, ((blk - 6144) * 256 + threadIdx.x) * 4);
  else                 conv4(wp, wpb, ((blk - 7872) * 256 + threadIdx.x) * 4);
}

// ---------------------------------------------------------------------------
// GEMM core: C[m0..+128][n0..+128] = sum_k A[m][k]*B[n][k], K=768 (B^T form).
// 256 threads = 4 waves (2x2); each wave: 64x64 = 4x4 C-frags.
// LDS tiles 128x64 bf16 staged via global_load_lds, XOR chunk swizzle.
// ---------------------------------------------------------------------------
__device__ __forceinline__ void gemm_tile_768(
    const u16* __restrict__ A, const u16* __restrict__ B,
    int m0, int n0, u16* ldsA, u16* ldsB, f32x4 acc[4][4])
{
  const int tid  = threadIdx.x;
  const int lane = tid & 63;
  const int wave = tid >> 6;
  const int quad = lane >> 4;
  const int l16  = lane & 15;
  const int wm = wave >> 1, wn = wave & 1;

  const u16* gA[4]; const u16* gB[4]; int ldsoff[4];
#pragma unroll
  for (int it = 0; it < 4; ++it) {
    const int c   = it * 256 + tid;        // flat 16B-chunk id, 1024 per tile
    const int row = c >> 3;
    const int cc  = (c & 7) ^ (row & 7);   // global chunk stored at slot c&7
    gA[it] = A + (size_t)(m0 + row) * 768 + cc * 8;
    gB[it] = B + (size_t)(n0 + row) * 768 + cc * 8;
    ldsoff[it] = (it * 256 + wave * 64) * 8;  // wave-uniform; HW adds lane*16B
  }

  for (int kt = 0; kt < 12; ++kt) {          // BK = 64, 768/64 = 12
    __syncthreads();
#pragma unroll
    for (int it = 0; it < 4; ++it) {
      gld_lds16(gA[it] + kt * 64, ldsA + ldsoff[it]);
      gld_lds16(gB[it] + kt * 64, ldsB + ldsoff[it]);
    }
    __syncthreads();
#pragma unroll
    for (int kc = 0; kc < 2; ++kc) {          // two K=32 MFMA chunks
      bf16x8 av[4], bv[4];
#pragma unroll
      for (int i = 0; i < 4; ++i) {
        const int rowA = wm * 64 + i * 16 + l16;
        av[i] = *(const bf16x8*)(ldsA + rowA * 64 + (((kc * 4 + quad) ^ (rowA & 7)) * 8));
        const int rowB = wn * 64 + i * 16 + l16;
        bv[i] = *(const bf16x8*)(ldsB + rowB * 64 + (((kc * 4 + quad) ^ (rowB & 7)) * 8));
      }
#pragma unroll
      for (int i = 0; i < 4; ++i)
#pragma unroll
        for (int j = 0; j < 4; ++j)
          acc[i][j] = MFMA_BF16(av[i], bv[j], acc[i][j]);
    }
  }
}

// C/D layout (m89/m91): within a 16x16 frag, row(m) = quad*4+reg, col(n) = lane&15.

// QKV GEMM with LDS-transposed coalesced epilogue. 768/128=6 => each n-block
// is entirely Q, K, or V (which = bx/6) and covers exactly 2 heads.
// Q/K blocks stage the 128x128 result as [token][feat] and store 128B rows;
// V blocks stage as [feat][token] and store Vt [B,H,D,N] rows directly.
__global__ __launch_bounds__(256, 4) void qkv_gemm_kernel(
    const u16* __restrict__ X, const u16* __restrict__ W,
    u16* __restrict__ Qb, u16* __restrict__ Kb, u16* __restrict__ Vt)
{
  __shared__ alignas(16) u16 lds[2 * 128 * 64];    // 32 KB: GEMM tiles, then ep
  u16* ldsA = lds;
  u16* ldsB = lds + 128 * 64;
  const int n0 = blockIdx.x * 128;   // 0..2176
  const int m0 = blockIdx.y * 128;   // 0..8064
  f32x4 acc[4][4];
  const f32x4 zero = {0.f, 0.f, 0.f, 0.f};
#pragma unroll
  for (int i = 0; i < 4; ++i)
#pragma unroll
    for (int j = 0; j < 4; ++j) acc[i][j] = zero;

  gemm_tile_768(X, W, m0, n0, ldsA, ldsB, acc);

  const int tid = threadIdx.x, lane = tid & 63, wave = tid >> 6;
  const int quad = lane >> 4, l16 = lane & 15;
  const int wm = wave >> 1, wn = wave & 1;

  const int which = blockIdx.x / 6;        // 0=Q 1=K 2=V (uniform per block)
  const bool isV = (which == 2);
  // Q scale: 64^-0.5 * log2(e) folded (attn uses exp2)
  const float sc = (which == 0) ? 0.180336880f : 1.0f;
  u16* ep = lds;                           // 128x128 bf16 view

  __syncthreads();                         // K-loop LDS frag reads done
#pragma unroll
  for (int i = 0; i < 4; ++i)
#pragma unroll
    for (int j = 0; j < 4; ++j)
#pragma unroll
      for (int r = 0; r < 4; ++r) {
        const int m_l = wm * 64 + i * 16 + quad * 4 + r;   // token-local
        const int o_l = wn * 64 + j * 16 + l16;            // feat-local
        const int row = isV ? o_l : m_l;
        const int col = isV ? m_l : o_l;
        const int ch  = col >> 3;
        const int chs = (ch & 8) | ((ch & 7) ^ (row & 7));
        ep[row * 128 + chs * 8 + (col & 7)] = f2bf(acc[i][j][r] * sc);
      }
  __syncthreads();

  // coalesced store: thread -> (row, half); 8 x dwordx4 = 128B per thread
  const int row  = tid >> 1, half = tid & 1;
  const int b_   = m0 >> 10;               // batch (1024 % 128 == 0)
  const int nb   = m0 & 1023;              // token base within batch
  const int oc0  = n0 - which * 768;       // feat base within segment
  u16* dst;
  if (!isV) {
    const int h = (oc0 >> 6) + half;       // 2 heads per block
    dst = (which == 0 ? Qb : Kb) + (((size_t)(b_ * 12 + h)) * 1024 + nb + row) * 64;
  } else {
    const int h = (oc0 >> 6) + (row >> 6);
    const int d = row & 63;
    dst = Vt + (((size_t)(b_ * 12 + h)) * 64 + d) * 1024 + nb + half * 64;
  }
#pragma unroll
  for (int c = 0; c < 8; ++c) {
    const int chs = half * 8 + (c ^ (row & 7));
    *(u32x4*)(dst + c * 8) = *(const u32x4*)(ep + row * 128 + chs * 8);
  }
}

// Proj GEMM: M128 x N128 tiles -> grid (6,64) = 384 blocks. Same inner core
// as qkv (identical per-element K accumulation order -> identical numerics).
// Epilogue: direct fp32 stores; each 16-lane quad writes 64B contiguous.
__global__ __launch_bounds__(256, 4) void proj_gemm_kernel(
    const u16* __restrict__ A, const u16* __restrict__ W,
    const float* __restrict__ bias, float* __restrict__ out)
{
  __shared__ alignas(16) u16 lds[2 * 128 * 64];    // 32 KB
  u16* ldsA = lds;
  u16* ldsB = lds + 128 * 64;
  const int n0 = blockIdx.x * 128;   // 0..640
  const int m0 = blockIdx.y * 128;   // 0..8064

  f32x4 acc[4][4];
  const f32x4 zero = {0.f, 0.f, 0.f, 0.f};
#pragma unroll
  for (int i = 0; i < 4; ++i)
#pragma unroll
    for (int j = 0; j < 4; ++j) acc[i][j] = zero;

  gemm_tile_768(A, W, m0, n0, ldsA, ldsB, acc);

  const int tid = threadIdx.x, lane = tid & 63, wave = tid >> 6;
  const int quad = lane >> 4, l16 = lane & 15;
  const int wm = wave >> 1, wn = wave & 1;

  float bv4[4];
#pragma unroll
  for (int j = 0; j < 4; ++j) bv4[j] = bias[n0 + wn * 64 + j * 16 + l16];

#pragma unroll
  for (int i = 0; i < 4; ++i)
#pragma unroll
    for (int j = 0; j < 4; ++j)
#pragma unroll
      for (int r = 0; r < 4; ++r) {
        const int m = m0 + wm * 64 + i * 16 + quad * 4 + r;
        out[(size_t)m * 768 + n0 + wn * 64 + j * 16 + l16] = acc[i][j][r] + bv4[j];
      }
}

// Attention v7: grid (96 heads, 8 q-blocks of 128), 256 threads = 4 waves,
// each wave 32 queries (2 strips of 16), full 1024-key sweep.
// T14 async-STAGE: K/V tile kt+1 is loaded global->reg DURING tile kt's
// compute; regs are ds_write'n to LDS after barrier (A). Raw s_barrier +
// counted waits (lgkmcnt(0) before barrier (B) only) — __syncthreads would
// drain vmcnt(0) and kill the overlap. Barrier (A) = WAR (all waves done
// reading LDS); barrier (B) = all waves' ds_writes visible.
// QK is computed TRANSPOSED (A=K-frag, B=Q-frag) so the C-layout hands each
// lane 4 consecutive keys of one P row -> packed b64 P-writes into wave-
// private pbuf; PV reads P rows as A-frags and Vt rows as B-frags.
// l-denominator: per-lane per-query(l16) scalar, quad-reduced in epilogue.
__global__ __launch_bounds__(256, 3) void attn_kernel(
    const u16* __restrict__ Q, const u16* __restrict__ K,
    const u16* __restrict__ Vt, __hip_bfloat16* __restrict__ O)
{
  __shared__ alignas(16) u16 ldsK[128 * 64];       // 16 KB: keys x d
  __shared__ alignas(16) u16 ldsV[64 * 128];       // 16 KB: d x keys
  __shared__ alignas(16) u16 pbuf[4 * 32 * 72];    // 18 KB: per-wave P slices
  const int bh = blockIdx.x;     // b*12 + h
  const int qb = blockIdx.y;     // 128-query block
  const int tid = threadIdx.x;
  const int wave = tid >> 6, lane = tid & 63;
  const int quad = lane >> 4, l16 = lane & 15;
  u16* pw = pbuf + wave * (32 * 72);

  const int q0 = qb * 128 + wave * 32;
  const u16* Kbh = K  + (size_t)bh * (1024 * 64);
  const u16* Vbh = Vt + (size_t)bh * (64 * 1024);

  // staging addresses: 4 chunks each of K and V (4 x 256 x 16B = 16 KB/tile).
  // Global addresses are pre-swizzled exactly as the old gld_lds path; LDS
  // destination is the linear chunk (it*256+tid)*16B -> identical layout.
  const u16* gK[4]; const u16* gV[4];
#pragma unroll
  for (int it = 0; it < 4; ++it) {
    const int c = it * 256 + tid;
    {   // K: [key 0..127][8 chunks]
      const int row = c >> 3, cc = (c & 7) ^ (row & 7);
      gK[it] = Kbh + (size_t)row * 64 + cc * 8;
    }
    {   // V: [d 0..63][16 chunks]
      const int row = c >> 4, slot = c & 15;
      const int cc = (slot & 8) | ((slot & 7) ^ (row & 7));
      gV[it] = Vbh + (size_t)row * 1024 + cc * 8;
    }
  }

  // Q frags (B[n=q=l16][k=quad*8+j]), resident for the whole loop
  bf16x8 aQ0[2], aQ1[2];
#pragma unroll
  for (int s = 0; s < 2; ++s) {
    const u16* qp = Q + ((size_t)bh * 1024 + q0 + s * 16 + l16) * 64 + quad * 8;
    aQ0[s] = *(const bf16x8*)qp;
    aQ1[s] = *(const bf16x8*)(qp + 32);
  }

  f32x4 oacc[2][4];
  const f32x4 zero = {0.f, 0.f, 0.f, 0.f};
#pragma unroll
  for (int s = 0; s < 2; ++s)
#pragma unroll
    for (int db = 0; db < 4; ++db) oacc[s][db] = zero;
  float lacc[2] = {0.f, 0.f};    // per-lane denom partial for query (s, l16)

  // prologue: tile 0 global->reg
  u32x4 rK[4], rV[4];
#pragma unroll
  for (int it = 0; it < 4; ++it) {
    rK[it] = *(const u32x4*)(gK[it]);
    rV[it] = *(const u32x4*)(gV[it]);
  }

  for (int kt = 0; kt < 8; ++kt) {        // 8 tiles of 128 keys
    asm volatile("" ::: "memory");
    __builtin_amdgcn_sched_barrier(0);
    __builtin_amdgcn_s_barrier();         // (A) all waves done reading LDS
    // regs -> LDS (compiler inserts the vmcnt waits for rK/rV arrival)
#pragma unroll
    for (int it = 0; it < 4; ++it) {
      *(u32x4*)(ldsK + (size_t)(it * 256 + tid) * 8) = rK[it];
      *(u32x4*)(ldsV + (size_t)(it * 256 + tid) * 8) = rV[it];
    }
    if (kt < 7) {                         // issue next tile's loads now;
#pragma unroll                            // they fly under this tile's compute
      for (int it = 0; it < 4; ++it) {
        rK[it] = *(const u32x4*)(gK[it] + (size_t)(kt + 1) * 128 * 64);
        rV[it] = *(const u32x4*)(gV[it] + (kt + 1) * 128);
      }
    }
    asm volatile("s_waitcnt lgkmcnt(0)" ::: "memory");  // own ds_writes done
    __builtin_amdgcn_sched_barrier(0);    // rule 18: no hoisting past the wait
    __builtin_amdgcn_s_barrier();         // (B) all writes visible
    __builtin_amdgcn_sched_barrier(0);

#pragma unroll
    for (int ph = 0; ph < 2; ++ph) {      // two 64-key phases per staged tile
      // K frags (A[m=key=l16-in-group][k=quad*8+j]) from LDS, shared by waves
      bf16x8 kb0[4], kb1[4];
#pragma unroll
      for (int t = 0; t < 4; ++t) {
        const int row = ph * 64 + t * 16 + l16;
        kb0[t] = *(const bf16x8*)(ldsK + row * 64 + (((0 * 4 + quad) ^ (row & 7)) * 8));
        kb1[t] = *(const bf16x8*)(ldsK + row * 64 + (((1 * 4 + quad) ^ (row & 7)) * 8));
      }
      asm volatile("" ::: "memory");  // WAR: prev phase's pa reads before stores
      // S^T = K Q^T (C: row=key quad*4+r, col=q l16); p = exp2;
      // packed b64 write into P[q][key] row (4 consecutive keys per lane)
#pragma unroll
      for (int s = 0; s < 2; ++s) {
#pragma unroll
        for (int t = 0; t < 4; ++t) {
          f32x4 z = zero;
          __builtin_amdgcn_s_setprio(1);
          z = MFMA_BF16(kb0[t], aQ0[s], z);
          z = MFMA_BF16(kb1[t], aQ1[s], z);
          __builtin_amdgcn_s_setprio(0);
          const float p0 = fast_exp2(z[0]);
          const float p1 = fast_exp2(z[1]);
          const float p2 = fast_exp2(z[2]);
          const float p3 = fast_exp2(z[3]);
          lacc[s] += (p0 + p1) + (p2 + p3);
          ushort4 pk;
          pk.x = f2bf(p0); pk.y = f2bf(p1); pk.z = f2bf(p2); pk.w = f2bf(p3);
          *(ushort4*)(pw + (s * 16 + l16) * 72 + t * 16 + quad * 4) = pk;
        }
      }
      asm volatile("" ::: "memory");  // RAW: P stores before reads (wave-priv)
      // P A-frags (A[m=q=l16][k=key=quad*8+j])
      bf16x8 pa0[2], pa1[2];
#pragma unroll
      for (int s = 0; s < 2; ++s) {
        const u16* pb = pw + (s * 16 + l16) * 72 + quad * 8;
        pa0[s] = *(const bf16x8*)pb;
        pa1[s] = *(const bf16x8*)(pb + 32);
      }
      // O += P V  (V frags from LDS as B[n=d=l16][k=key], reused across s)
      __builtin_amdgcn_s_setprio(1);
#pragma unroll
      for (int db = 0; db < 4; ++db) {
        const int d = db * 16 + l16;
        const bf16x8 v0 = *(const bf16x8*)(ldsV + d * 128 + (ph * 8 + ((0 * 4 + quad) ^ (d & 7))) * 8);
        const bf16x8 v1 = *(const bf16x8*)(ldsV + d * 128 + (ph * 8 + ((1 * 4 + quad) ^ (d & 7))) * 8);
#pragma unroll
        for (int s = 0; s < 2; ++s) {
          oacc[s][db] = MFMA_BF16(pa0[s], v0, oacc[s][db]);
          oacc[s][db] = MFMA_BF16(pa1[s], v1, oacc[s][db]);
        }
      }
      __builtin_amdgcn_s_setprio(0);
    }
  }

  // epilogue: full denom per query (s,l16) = quad-reduce; broadcast to the
  // oacc row layout (row=q=quad*4+r, col=d=l16) via shfl, write O.
  const int b = bh / 12, h = bh - (bh / 12) * 12;
  float linv[2];
#pragma unroll
  for (int s = 0; s < 2; ++s) {
    float l = lacc[s];
    l += __shfl_xor(l, 16);
    l += __shfl_xor(l, 32);
    linv[s] = 1.f / l;        // uniform across quads; indexed by l16
  }
#pragma unroll
  for (int s = 0; s < 2; ++s) {
#pragma unroll
    for (int r = 0; r < 4; ++r) {
      const float inv = __shfl(linv[s], quad * 4 + r);   // denom of query row
      const int n = q0 + s * 16 + quad * 4 + r;
      __hip_bfloat16* orow = O + ((size_t)b * 1024 + n) * 768 + h * 64;
#pragma unroll
      for (int db = 0; db < 4; ++db)
        orow[db * 16 + l16] = __float2bfloat16(oacc[s][db][r] * inv);
    }
  }
}

extern "C" void kernel_launch(void* const* d_in, const int* in_sizes, int n_in,
                              void* d_out, int out_size, void* d_ws, size_t ws_size,
                              hipStream_t stream) {
  const float* x      = (const float*)d_in[0];   // [8,1024,768] fp32
  const float* w_qkv  = (const float*)d_in[1];   // [2304,768]  fp32
  const float* w_proj = (const float*)d_in[2];   // [768,768]   fp32
  const float* b_proj = (const float*)d_in[3];   // [768]       fp32
  float* out = (float*)d_out;                    // [8,1024,768] fp32

  char* ws = (char*)d_ws;
  const size_t SEG = (size_t)96 * 1024 * 64 * sizeof(u16);  // 12.58 MB
  u16* xb   = (u16*)(ws + 0 * SEG);              // x as bf16 [8192,768]
  u16* Qb   = (u16*)(ws + 1 * SEG);
  u16* Kb   = (u16*)(ws + 2 * SEG);
  u16* AO   = (u16*)(ws + 3 * SEG);              // attn out [8192,768] bf16
  u16* Vt   = (u16*)(ws + 4 * SEG);              // V^T [B,H,D,N]
  u16* wqb  = (u16*)(ws + 5 * SEG);              // w_qkv bf16 (3.54 MB)
  u16* wpb  = (u16*)(ws + 5 * SEG + 3538944);    // w_proj bf16 (1.18 MB)

  convert3_kernel<<<8448, 256, 0, stream>>>(x, xb, w_qkv, wqb, w_proj, wpb);
  qkv_gemm_kernel<<<dim3(18, 64), 256, 0, stream>>>(xb, wqb, Qb, Kb, Vt);
  attn_kernel    <<<dim3(96, 8), 256, 0, stream>>>(Qb, Kb, Vt, (__hip_bfloat16*)AO);
  proj_gemm_kernel<<<dim3(6, 64), 256, 0, stream>>>(AO, wpb, b_proj, out);
}

// Round 4
// 185.896 us; speedup vs baseline: 1.2067x; 1.2067x over previous
//
#include <hip/hip_runtime.h>
#include <hip/hip_bf16.h>
#include <math.h>

// Attention_10840497455414: x[8,1024,768] fp32 -> QKV -> 12-head attention ->
// proj+bias -> fp32 out. Compute in bf16 MFMA (16x16x32), fp32 accumulation.
//
// Pipeline (intermediates bf16 in d_ws). 4 launches:
//   0) convert3  : one kernel converts x, w_qkv, w_proj fp32->bf16
//   1) qkv_gemm  : [8192,768] x [2304,768]^T -> Q(scaled by 1/8*log2e)/K/Vt
//                  LDS-transposed coalesced epilogue; V emitted as Vt directly.
//                  launch_bounds(256,4). R11 lesson: (256,5) crashed the
//                  harness — VGPR_Count=60 is ArchVGPRs only; +64 AGPRs for
//                  acc[4][4] = ~124 regs/wave > 512/5 budget. Do NOT raise.
//   2) attn v8   : R13. R12's T14 reg-staging SPILLED (WRITE_SIZE 220MB =
//                  scratch traffic, attn 46->84us). v8 keeps the overlap but
//                  with zero-VGPR staging: double-buffered global_load_lds,
//                  64-key tiles (2x8KB K + 2x8KB V + 18KB pbuf = 50KB, still
//                  3 blocks/CU). Per tile: vmcnt(0) -> s_barrier -> issue
//                  prefetch(kt+1) -> compute(kt). Prefetch flies under
//                  compute; barrier protects WAR on the other buffer.
//                  Key accumulation order identical to v6 -> same numerics.
//   3) proj_gemm : M128xN128 reusing gemm_tile_768 -> grid (6,64)=384 blocks.

typedef unsigned short u16;
typedef __attribute__((ext_vector_type(8))) short bf16x8;   // 8 bf16 = 4 VGPRs
typedef __attribute__((ext_vector_type(4))) float f32x4;    // MFMA C/D
typedef __attribute__((ext_vector_type(4))) unsigned int u32x4;

#define MFMA_BF16(a, b, c) __builtin_amdgcn_mfma_f32_16x16x32_bf16((a), (b), (c), 0, 0, 0)

static __device__ __forceinline__ void gld_lds16(const void* g, void* l) {
  __builtin_amdgcn_global_load_lds(
      (__attribute__((address_space(1))) void*)(g),
      (__attribute__((address_space(3))) void*)(l), 16, 0, 0);
}

static __device__ __forceinline__ u16 f2bf(float f) {
  __hip_bfloat16 h = __float2bfloat16(f);
  return *(u16*)&h;
}

static __device__ __forceinline__ float fast_exp2(float x) {
#if __has_builtin(__builtin_amdgcn_exp2f)
  return __builtin_amdgcn_exp2f(x);   // raw v_exp_f32 (D = 2^S0)
#else
  return exp2f(x);
#endif
}

// fp32 -> bf16 (RNE), non-finite sanitized to 0. 4 elems per thread.
static __device__ __forceinline__ void conv4(const float* src, u16* dst, int i) {
  const float4 v = *(const float4*)(src + i);
  float f0 = v.x, f1 = v.y, f2 = v.z, f3 = v.w;
  if (!isfinite(f0)) f0 = 0.f;
  if (!isfinite(f1)) f1 = 0.f;
  if (!isfinite(f2)) f2 = 0.f;
  if (!isfinite(f3)) f3 = 0.f;
  ushort4 o;
  o.x = f2bf(f0); o.y = f2bf(f1); o.z = f2bf(f2); o.w = f2bf(f3);
  *(ushort4*)(dst + i) = o;
}

// one launch for all three conversions (x: 6144 blocks, wq: 1728, wp: 576)
__global__ __launch_bounds__(256) void convert3_kernel(
    const float* __restrict__ x,  u16* __restrict__ xb,
    const float* __restrict__ wq, u16* __restrict__ wqb,
    const float* __restrict__ wp, u16* __restrict__ wpb)
{
  const int blk = blockIdx.x;
  if (blk < 6144)      conv4(x,  xb,  (blk * 256 + threadIdx.x) * 4);
  else if (blk < 7872) conv4(wq, wqb, ((blk - 6144) * 256 + threadIdx.x) * 4);
  else                 conv4(wp, wpb, ((blk - 7872) * 256 + threadIdx.x) * 4);
}

// ---------------------------------------------------------------------------
// GEMM core: C[m0..+128][n0..+128] = sum_k A[m][k]*B[n][k], K=768 (B^T form).
// 256 threads = 4 waves (2x2); each wave: 64x64 = 4x4 C-frags.
// LDS tiles 128x64 bf16 staged via global_load_lds, XOR chunk swizzle.
// ---------------------------------------------------------------------------
__device__ __forceinline__ void gemm_tile_768(
    const u16* __restrict__ A, const u16* __restrict__ B,
    int m0, int n0, u16* ldsA, u16* ldsB, f32x4 acc[4][4])
{
  const int tid  = threadIdx.x;
  const int lane = tid & 63;
  const int wave = tid >> 6;
  const int quad = lane >> 4;
  const int l16  = lane & 15;
  const int wm = wave >> 1, wn = wave & 1;

  const u16* gA[4]; const u16* gB[4]; int ldsoff[4];
#pragma unroll
  for (int it = 0; it < 4; ++it) {
    const int c   = it * 256 + tid;        // flat 16B-chunk id, 1024 per tile
    const int row = c >> 3;
    const int cc  = (c & 7) ^ (row & 7);   // global chunk stored at slot c&7
    gA[it] = A + (size_t)(m0 + row) * 768 + cc * 8;
    gB[it] = B + (size_t)(n0 + row) * 768 + cc * 8;
    ldsoff[it] = (it * 256 + wave * 64) * 8;  // wave-uniform; HW adds lane*16B
  }

  for (int kt = 0; kt < 12; ++kt) {          // BK = 64, 768/64 = 12
    __syncthreads();
#pragma unroll
    for (int it = 0; it < 4; ++it) {
      gld_lds16(gA[it] + kt * 64, ldsA + ldsoff[it]);
      gld_lds16(gB[it] + kt * 64, ldsB + ldsoff[it]);
    }
    __syncthreads();
#pragma unroll
    for (int kc = 0; kc < 2; ++kc) {          // two K=32 MFMA chunks
      bf16x8 av[4], bv[4];
#pragma unroll
      for (int i = 0; i < 4; ++i) {
        const int rowA = wm * 64 + i * 16 + l16;
        av[i] = *(const bf16x8*)(ldsA + rowA * 64 + (((kc * 4 + quad) ^ (rowA & 7)) * 8));
        const int rowB = wn * 64 + i * 16 + l16;
        bv[i] = *(const bf16x8*)(ldsB + rowB * 64 + (((kc * 4 + quad) ^ (rowB & 7)) * 8));
      }
#pragma unroll
      for (int i = 0; i < 4; ++i)
#pragma unroll
        for (int j = 0; j < 4; ++j)
          acc[i][j] = MFMA_BF16(av[i], bv[j], acc[i][j]);
    }
  }
}

// C/D layout (m89/m91): within a 16x16 frag, row(m) = quad*4+reg, col(n) = lane&15.

// QKV GEMM with LDS-transposed coalesced epilogue. 768/128=6 => each n-block
// is entirely Q, K, or V (which = bx/6) and covers exactly 2 heads.
// Q/K blocks stage the 128x128 result as [token][feat] and store 128B rows;
// V blocks stage as [feat][token] and store Vt [B,H,D,N] rows directly.
__global__ __launch_bounds__(256, 4) void qkv_gemm_kernel(
    const u16* __restrict__ X, const u16* __restrict__ W,
    u16* __restrict__ Qb, u16* __restrict__ Kb, u16* __restrict__ Vt)
{
  __shared__ alignas(16) u16 lds[2 * 128 * 64];    // 32 KB: GEMM tiles, then ep
  u16* ldsA = lds;
  u16* ldsB = lds + 128 * 64;
  const int n0 = blockIdx.x * 128;   // 0..2176
  const int m0 = blockIdx.y * 128;   // 0..8064
  f32x4 acc[4][4];
  const f32x4 zero = {0.f, 0.f, 0.f, 0.f};
#pragma unroll
  for (int i = 0; i < 4; ++i)
#pragma unroll
    for (int j = 0; j < 4; ++j) acc[i][j] = zero;

  gemm_tile_768(X, W, m0, n0, ldsA, ldsB, acc);

  const int tid = threadIdx.x, lane = tid & 63, wave = tid >> 6;
  const int quad = lane >> 4, l16 = lane & 15;
  const int wm = wave >> 1, wn = wave & 1;

  const int which = blockIdx.x / 6;        // 0=Q 1=K 2=V (uniform per block)
  const bool isV = (which == 2);
  // Q scale: 64^-0.5 * log2(e) folded (attn uses exp2)
  const float sc = (which == 0) ? 0.180336880f : 1.0f;
  u16* ep = lds;                           // 128x128 bf16 view

  __syncthreads();                         // K-loop LDS frag reads done
#pragma unroll
  for (int i = 0; i < 4; ++i)
#pragma unroll
    for (int j = 0; j < 4; ++j)
#pragma unroll
      for (int r = 0; r < 4; ++r) {
        const int m_l = wm * 64 + i * 16 + quad * 4 + r;   // token-local
        const int o_l = wn * 64 + j * 16 + l16;            // feat-local
        const int row = isV ? o_l : m_l;
        const int col = isV ? m_l : o_l;
        const int ch  = col >> 3;
        const int chs = (ch & 8) | ((ch & 7) ^ (row & 7));
        ep[row * 128 + chs * 8 + (col & 7)] = f2bf(acc[i][j][r] * sc);
      }
  __syncthreads();

  // coalesced store: thread -> (row, half); 8 x dwordx4 = 128B per thread
  const int row  = tid >> 1, half = tid & 1;
  const int b_   = m0 >> 10;               // batch (1024 % 128 == 0)
  const int nb   = m0 & 1023;              // token base within batch
  const int oc0  = n0 - which * 768;       // feat base within segment
  u16* dst;
  if (!isV) {
    const int h = (oc0 >> 6) + half;       // 2 heads per block
    dst = (which == 0 ? Qb : Kb) + (((size_t)(b_ * 12 + h)) * 1024 + nb + row) * 64;
  } else {
    const int h = (oc0 >> 6) + (row >> 6);
    const int d = row & 63;
    dst = Vt + (((size_t)(b_ * 12 + h)) * 64 + d) * 1024 + nb + half * 64;
  }
#pragma unroll
  for (int c = 0; c < 8; ++c) {
    const int chs = half * 8 + (c ^ (row & 7));
    *(u32x4*)(dst + c * 8) = *(const u32x4*)(ep + row * 128 + chs * 8);
  }
}

// Proj GEMM: M128 x N128 tiles -> grid (6,64) = 384 blocks. Same inner core
// as qkv (identical per-element K accumulation order -> identical numerics).
// Epilogue: direct fp32 stores; each 16-lane quad writes 64B contiguous.
__global__ __launch_bounds__(256, 4) void proj_gemm_kernel(
    const u16* __restrict__ A, const u16* __restrict__ W,
    const float* __restrict__ bias, float* __restrict__ out)
{
  __shared__ alignas(16) u16 lds[2 * 128 * 64];    // 32 KB
  u16* ldsA = lds;
  u16* ldsB = lds + 128 * 64;
  const int n0 = blockIdx.x * 128;   // 0..640
  const int m0 = blockIdx.y * 128;   // 0..8064

  f32x4 acc[4][4];
  const f32x4 zero = {0.f, 0.f, 0.f, 0.f};
#pragma unroll
  for (int i = 0; i < 4; ++i)
#pragma unroll
    for (int j = 0; j < 4; ++j) acc[i][j] = zero;

  gemm_tile_768(A, W, m0, n0, ldsA, ldsB, acc);

  const int tid = threadIdx.x, lane = tid & 63, wave = tid >> 6;
  const int quad = lane >> 4, l16 = lane & 15;
  const int wm = wave >> 1, wn = wave & 1;

  float bv4[4];
#pragma unroll
  for (int j = 0; j < 4; ++j) bv4[j] = bias[n0 + wn * 64 + j * 16 + l16];

#pragma unroll
  for (int i = 0; i < 4; ++i)
#pragma unroll
    for (int j = 0; j < 4; ++j)
#pragma unroll
      for (int r = 0; r < 4; ++r) {
        const int m = m0 + wm * 64 + i * 16 + quad * 4 + r;
        out[(size_t)m * 768 + n0 + wn * 64 + j * 16 + l16] = acc[i][j][r] + bv4[j];
      }
}

// Attention v8: grid (96 heads, 8 q-blocks of 128), 256 threads = 4 waves,
// each wave 32 queries (2 strips of 16), full 1024-key sweep.
// 16 tiles of 64 keys, double-buffered gld_lds staging (zero VGPR cost):
//   per tile: vmcnt(0) -> s_barrier -> issue gld_lds(kt+1 -> other buf)
//             -> compute tile kt.
// The prefetch overlaps compute; the barrier (which every wave reaches only
// after finishing tile kt-1's LDS reads) makes the buffer swap WAR-safe.
// QK is computed TRANSPOSED (A=K-frag, B=Q-frag) so the C-layout hands each
// lane 4 consecutive keys of one P row -> packed b64 P-writes into wave-
// private pbuf; PV reads P rows as A-frags and Vt rows as B-frags.
// l-denominator: per-lane per-query(l16) scalar, quad-reduced in epilogue.
__global__ __launch_bounds__(256, 3) void attn_kernel(
    const u16* __restrict__ Q, const u16* __restrict__ K,
    const u16* __restrict__ Vt, __hip_bfloat16* __restrict__ O)
{
  __shared__ alignas(16) u16 ldsK[2 * 64 * 64];    // 16 KB: 2 bufs, keys x d
  __shared__ alignas(16) u16 ldsV[2 * 64 * 64];    // 16 KB: 2 bufs, d x keys
  __shared__ alignas(16) u16 pbuf[4 * 32 * 72];    // 18 KB: per-wave P slices
  const int bh = blockIdx.x;     // b*12 + h
  const int qb = blockIdx.y;     // 128-query block
  const int tid = threadIdx.x;
  const int wave = tid >> 6, lane = tid & 63;
  const int quad = lane >> 4, l16 = lane & 15;
  u16* pw = pbuf + wave * (32 * 72);

  const int q0 = qb * 128 + wave * 32;
  const u16* Kbh = K  + (size_t)bh * (1024 * 64);
  const u16* Vbh = Vt + (size_t)bh * (64 * 1024);

  // staging addresses: 2 issues each of K and V per 64-key tile
  // (2 x 256 x 16B = 8 KB per array per tile). Global addresses pre-swizzled;
  // LDS destination is the linear chunk (it*256+tid)*16B.
  const u16* gK[2]; const u16* gV[2]; int loK[2], loV[2];
#pragma unroll
  for (int it = 0; it < 2; ++it) {
    const int c = it * 256 + tid;          // 0..511
    {   // K tile: [key 0..63][8 chunks of 8 d-elems]
      const int row = c >> 3, cc = (c & 7) ^ (row & 7);
      gK[it] = Kbh + (size_t)row * 64 + cc * 8;
      loK[it] = (it * 256 + wave * 64) * 8;
    }
    {   // V tile: [d 0..63][8 chunks of 8 keys]
      const int row = c >> 3, cc = (c & 7) ^ (row & 7);
      gV[it] = Vbh + (size_t)row * 1024 + cc * 8;
      loV[it] = (it * 256 + wave * 64) * 8;
    }
  }

  // Q frags (B[n=q=l16][k=quad*8+j]), resident for the whole loop
  bf16x8 aQ0[2], aQ1[2];
#pragma unroll
  for (int s = 0; s < 2; ++s) {
    const u16* qp = Q + ((size_t)bh * 1024 + q0 + s * 16 + l16) * 64 + quad * 8;
    aQ0[s] = *(const bf16x8*)qp;
    aQ1[s] = *(const bf16x8*)(qp + 32);
  }

  f32x4 oacc[2][4];
  const f32x4 zero = {0.f, 0.f, 0.f, 0.f};
#pragma unroll
  for (int s = 0; s < 2; ++s)
#pragma unroll
    for (int db = 0; db < 4; ++db) oacc[s][db] = zero;
  float lacc[2] = {0.f, 0.f};    // per-lane denom partial for query (s, l16)

  // prologue: stage tile 0 into buffer 0
#pragma unroll
  for (int it = 0; it < 2; ++it) {
    gld_lds16(gK[it], ldsK + loK[it]);
    gld_lds16(gV[it], ldsV + loV[it]);
  }

#pragma unroll 2
  for (int kt = 0; kt < 16; ++kt) {       // 16 tiles of 64 keys
    const int cur = (kt & 1) * 4096;      // u16 offset of current buffer
    asm volatile("s_waitcnt vmcnt(0)" ::: "memory");   // buf[cur] landed
    __builtin_amdgcn_sched_barrier(0);
    __builtin_amdgcn_s_barrier();         // all staging visible + prev tile's
    __builtin_amdgcn_sched_barrier(0);    // LDS reads done (WAR for nxt buf)
    if (kt < 15) {                        // prefetch kt+1 under this compute
      const int nxt = ((kt + 1) & 1) * 4096;
#pragma unroll
      for (int it = 0; it < 2; ++it) {
        gld_lds16(gK[it] + (size_t)(kt + 1) * (64 * 64), ldsK + nxt + loK[it]);
        gld_lds16(gV[it] + (kt + 1) * 64, ldsV + nxt + loV[it]);
      }
    }

    // K frags (A[m=key=l16-in-group][k=quad*8+j]) from LDS, shared by waves
    bf16x8 kb0[4], kb1[4];
#pragma unroll
    for (int t = 0; t < 4; ++t) {
      const int row = t * 16 + l16;
      kb0[t] = *(const bf16x8*)(ldsK + cur + row * 64 + (((0 * 4 + quad) ^ (row & 7)) * 8));
      kb1[t] = *(const bf16x8*)(ldsK + cur + row * 64 + (((1 * 4 + quad) ^ (row & 7)) * 8));
    }
    asm volatile("" ::: "memory");  // WAR: prev tile's pa reads before stores
    // S^T = K Q^T (C: row=key quad*4+r, col=q l16); p = exp2;
    // packed b64 write into P[q][key] row (4 consecutive keys per lane)
#pragma unroll
    for (int s = 0; s < 2; ++s) {
#pragma unroll
      for (int t = 0; t < 4; ++t) {
        f32x4 z = zero;
        z = MFMA_BF16(kb0[t], aQ0[s], z);
        z = MFMA_BF16(kb1[t], aQ1[s], z);
        const float p0 = fast_exp2(z[0]);
        const float p1 = fast_exp2(z[1]);
        const float p2 = fast_exp2(z[2]);
        const float p3 = fast_exp2(z[3]);
        lacc[s] += (p0 + p1) + (p2 + p3);
        ushort4 pk;
        pk.x = f2bf(p0); pk.y = f2bf(p1); pk.z = f2bf(p2); pk.w = f2bf(p3);
        *(ushort4*)(pw + (s * 16 + l16) * 72 + t * 16 + quad * 4) = pk;
      }
    }
    asm volatile("" ::: "memory");  // RAW: P stores before reads (wave-priv)
    // P A-frags (A[m=q=l16][k=key=quad*8+j])
    bf16x8 pa0[2], pa1[2];
#pragma unroll
    for (int s = 0; s < 2; ++s) {
      const u16* pb = pw + (s * 16 + l16) * 72 + quad * 8;
      pa0[s] = *(const bf16x8*)pb;
      pa1[s] = *(const bf16x8*)(pb + 32);
    }
    // O += P V  (V frags from LDS as B[n=d=l16][k=key], reused across s)
#pragma unroll
    for (int db = 0; db < 4; ++db) {
      const int d = db * 16 + l16;
      const bf16x8 v0 = *(const bf16x8*)(ldsV + cur + d * 64 + (((0 * 4 + quad) ^ (d & 7))) * 8);
      const bf16x8 v1 = *(const bf16x8*)(ldsV + cur + d * 64 + (((1 * 4 + quad) ^ (d & 7))) * 8);
#pragma unroll
      for (int s = 0; s < 2; ++s) {
        oacc[s][db] = MFMA_BF16(pa0[s], v0, oacc[s][db]);
        oacc[s][db] = MFMA_BF16(pa1[s], v1, oacc[s][db]);
      }
    }
  }

  // epilogue: full denom per query (s,l16) = quad-reduce; broadcast to the
  // oacc row layout (row=q=quad*4+r, col=d=l16) via shfl, write O.
  const int b = bh / 12, h = bh - (bh / 12) * 12;
  float linv[2];
#pragma unroll
  for (int s = 0; s < 2; ++s) {
    float l = lacc[s];
    l += __shfl_xor(l, 16);
    l += __shfl_xor(l, 32);
    linv[s] = 1.f / l;        // uniform across quads; indexed by l16
  }
#pragma unroll
  for (int s = 0; s < 2; ++s) {
#pragma unroll
    for (int r = 0; r < 4; ++r) {
      const float inv = __shfl(linv[s], quad * 4 + r);   // denom of query row
      const int n = q0 + s * 16 + quad * 4 + r;
      __hip_bfloat16* orow = O + ((size_t)b * 1024 + n) * 768 + h * 64;
#pragma unroll
      for (int db = 0; db < 4; ++db)
        orow[db * 16 + l16] = __float2bfloat16(oacc[s][db][r] * inv);
    }
  }
}

extern "C" void kernel_launch(void* const* d_in, const int* in_sizes, int n_in,
                              void* d_out, int out_size, void* d_ws, size_t ws_size,
                              hipStream_t stream) {
  const float* x      = (const float*)d_in[0];   // [8,1024,768] fp32
  const float* w_qkv  = (const float*)d_in[1];   // [2304,768]  fp32
  const float* w_proj = (const float*)d_in[2];   // [768,768]   fp32
  const float* b_proj = (const float*)d_in[3];   // [768]       fp32
  float* out = (float*)d_out;                    // [8,1024,768] fp32

  char* ws = (char*)d_ws;
  const size_t SEG = (size_t)96 * 1024 * 64 * sizeof(u16);  // 12.58 MB
  u16* xb   = (u16*)(ws + 0 * SEG);              // x as bf16 [8192,768]
  u16* Qb   = (u16*)(ws + 1 * SEG);
  u16* Kb   = (u16*)(ws + 2 * SEG);
  u16* AO   = (u16*)(ws + 3 * SEG);              // attn out [8192,768] bf16
  u16* Vt   = (u16*)(ws + 4 * SEG);              // V^T [B,H,D,N]
  u16* wqb  = (u16*)(ws + 5 * SEG);              // w_qkv bf16 (3.54 MB)
  u16* wpb  = (u16*)(ws + 5 * SEG + 3538944);    // w_proj bf16 (1.18 MB)

  convert3_kernel<<<8448, 256, 0, stream>>>(x, xb, w_qkv, wqb, w_proj, wpb);
  qkv_gemm_kernel<<<dim3(18, 64), 256, 0, stream>>>(xb, wqb, Qb, Kb, Vt);
  attn_kernel    <<<dim3(96, 8), 256, 0, stream>>>(Qb, Kb, Vt, (__hip_bfloat16*)AO);
  proj_gemm_kernel<<<dim3(6, 64), 256, 0, stream>>>(AO, wpb, b_proj, out);
}

// Round 5
// 181.581 us; speedup vs baseline: 1.2354x; 1.0238x over previous
//
#include <hip/hip_runtime.h>
#include <hip/hip_bf16.h>
#include <math.h>

// Attention_10840497455414: x[8,1024,768] fp32 -> QKV -> 12-head attention ->
// proj+bias -> fp32 out. Compute in bf16 MFMA (16x16x32), fp32 accumulation.
//
// Pipeline (intermediates bf16 in d_ws). 4 launches:
//   0) convert3  : one kernel converts x, w_qkv, w_proj fp32->bf16
//   1) qkv_gemm  : [8192,768] x [2304,768]^T -> Q(scaled by 1/8*log2e)/K/Vt
//                  LDS-transposed coalesced epilogue; V emitted as Vt directly.
//                  launch_bounds(256,4). R11 lesson: (256,5) crashed the
//                  harness — VGPR_Count=60 is ArchVGPRs only; +64 AGPRs for
//                  acc[4][4] = ~124 regs/wave > 512/5 budget. Do NOT raise.
//                  R14: T1 chunked XCD swizzle (1152 blocks = 8*144 exactly):
//                  R4-counter FETCH_SIZE was 66MB vs 16MB ideal — X panels
//                  pulled into ~8 XCD L2s each. Swizzle gives each XCD 8
//                  contiguous m-rows x all n (1.6MB X + 3.5MB W ~ L2-fit).
//   2) attn v8   : 64-key tiles, double-buffered gld_lds staging (zero VGPR),
//                  vmcnt(0)->s_barrier->prefetch->compute. Grid (96,8) is
//                  natively XCD-local per head (96 % 8 == 0) — no swizzle.
//   3) proj_gemm : M128xN128, grid (6,64)=384 blocks = 8*48 -> same swizzle.

typedef unsigned short u16;
typedef __attribute__((ext_vector_type(8))) short bf16x8;   // 8 bf16 = 4 VGPRs
typedef __attribute__((ext_vector_type(4))) float f32x4;    // MFMA C/D
typedef __attribute__((ext_vector_type(4))) unsigned int u32x4;

#define MFMA_BF16(a, b, c) __builtin_amdgcn_mfma_f32_16x16x32_bf16((a), (b), (c), 0, 0, 0)

static __device__ __forceinline__ void gld_lds16(const void* g, void* l) {
  __builtin_amdgcn_global_load_lds(
      (__attribute__((address_space(1))) void*)(g),
      (__attribute__((address_space(3))) void*)(l), 16, 0, 0);
}

static __device__ __forceinline__ u16 f2bf(float f) {
  __hip_bfloat16 h = __float2bfloat16(f);
  return *(u16*)&h;
}

static __device__ __forceinline__ float fast_exp2(float x) {
#if __has_builtin(__builtin_amdgcn_exp2f)
  return __builtin_amdgcn_exp2f(x);   // raw v_exp_f32 (D = 2^S0)
#else
  return exp2f(x);
#endif
}

// fp32 -> bf16 (RNE), non-finite sanitized to 0. 4 elems per thread.
static __device__ __forceinline__ void conv4(const float* src, u16* dst, int i) {
  const float4 v = *(const float4*)(src + i);
  float f0 = v.x, f1 = v.y, f2 = v.z, f3 = v.w;
  if (!isfinite(f0)) f0 = 0.f;
  if (!isfinite(f1)) f1 = 0.f;
  if (!isfinite(f2)) f2 = 0.f;
  if (!isfinite(f3)) f3 = 0.f;
  ushort4 o;
  o.x = f2bf(f0); o.y = f2bf(f1); o.z = f2bf(f2); o.w = f2bf(f3);
  *(ushort4*)(dst + i) = o;
}

// one launch for all three conversions (x: 6144 blocks, wq: 1728, wp: 576)
__global__ __launch_bounds__(256) void convert3_kernel(
    const float* __restrict__ x,  u16* __restrict__ xb,
    const float* __restrict__ wq, u16* __restrict__ wqb,
    const float* __restrict__ wp, u16* __restrict__ wpb)
{
  const int blk = blockIdx.x;
  if (blk < 6144)      conv4(x,  xb,  (blk * 256 + threadIdx.x) * 4);
  else if (blk < 7872) conv4(wq, wqb, ((blk - 6144) * 256 + threadIdx.x) * 4);
  else                 conv4(wp, wpb, ((blk - 7872) * 256 + threadIdx.x) * 4);
}

// ---------------------------------------------------------------------------
// GEMM core: C[m0..+128][n0..+128] = sum_k A[m][k]*B[n][k], K=768 (B^T form).
// 256 threads = 4 waves (2x2); each wave: 64x64 = 4x4 C-frags.
// LDS tiles 128x64 bf16 staged via global_load_lds, XOR chunk swizzle.
// ---------------------------------------------------------------------------
__device__ __forceinline__ void gemm_tile_768(
    const u16* __restrict__ A, const u16* __restrict__ B,
    int m0, int n0, u16* ldsA, u16* ldsB, f32x4 acc[4][4])
{
  const int tid  = threadIdx.x;
  const int lane = tid & 63;
  const int wave = tid >> 6;
  const int quad = lane >> 4;
  const int l16  = lane & 15;
  const int wm = wave >> 1, wn = wave & 1;

  const u16* gA[4]; const u16* gB[4]; int ldsoff[4];
#pragma unroll
  for (int it = 0; it < 4; ++it) {
    const int c   = it * 256 + tid;        // flat 16B-chunk id, 1024 per tile
    const int row = c >> 3;
    const int cc  = (c & 7) ^ (row & 7);   // global chunk stored at slot c&7
    gA[it] = A + (size_t)(m0 + row) * 768 + cc * 8;
    gB[it] = B + (size_t)(n0 + row) * 768 + cc * 8;
    ldsoff[it] = (it * 256 + wave * 64) * 8;  // wave-uniform; HW adds lane*16B
  }

  for (int kt = 0; kt < 12; ++kt) {          // BK = 64, 768/64 = 12
    __syncthreads();
#pragma unroll
    for (int it = 0; it < 4; ++it) {
      gld_lds16(gA[it] + kt * 64, ldsA + ldsoff[it]);
      gld_lds16(gB[it] + kt * 64, ldsB + ldsoff[it]);
    }
    __syncthreads();
#pragma unroll
    for (int kc = 0; kc < 2; ++kc) {          // two K=32 MFMA chunks
      bf16x8 av[4], bv[4];
#pragma unroll
      for (int i = 0; i < 4; ++i) {
        const int rowA = wm * 64 + i * 16 + l16;
        av[i] = *(const bf16x8*)(ldsA + rowA * 64 + (((kc * 4 + quad) ^ (rowA & 7)) * 8));
        const int rowB = wn * 64 + i * 16 + l16;
        bv[i] = *(const bf16x8*)(ldsB + rowB * 64 + (((kc * 4 + quad) ^ (rowB & 7)) * 8));
      }
#pragma unroll
      for (int i = 0; i < 4; ++i)
#pragma unroll
        for (int j = 0; j < 4; ++j)
          acc[i][j] = MFMA_BF16(av[i], bv[j], acc[i][j]);
    }
  }
}

// C/D layout (m89/m91): within a 16x16 frag, row(m) = quad*4+reg, col(n) = lane&15.

// QKV GEMM with LDS-transposed coalesced epilogue. 768/128=6 => each n-block
// is entirely Q, K, or V (which = bx/6) and covers exactly 2 heads.
// Q/K blocks stage the 128x128 result as [token][feat] and store 128B rows;
// V blocks stage as [feat][token] and store Vt [B,H,D,N] rows directly.
__global__ __launch_bounds__(256, 4) void qkv_gemm_kernel(
    const u16* __restrict__ X, const u16* __restrict__ W,
    u16* __restrict__ Qb, u16* __restrict__ Kb, u16* __restrict__ Vt)
{
  __shared__ alignas(16) u16 lds[2 * 128 * 64];    // 32 KB: GEMM tiles, then ep
  u16* ldsA = lds;
  u16* ldsB = lds + 128 * 64;

  // T1 chunked XCD swizzle: 1152 blocks = 8 XCDs x 144. XCD k executes swz in
  // [144k,144(k+1)) => 8 contiguous m-rows x all 18 n-blocks per XCD.
  const int id0 = blockIdx.y * 18 + blockIdx.x;    // dispatch-order id
  const int swz = (id0 & 7) * 144 + (id0 >> 3);    // bijective (1152%8==0)
  const int bx  = swz % 18, by = swz / 18;
  const int n0 = bx * 128;           // 0..2176
  const int m0 = by * 128;           // 0..8064
  f32x4 acc[4][4];
  const f32x4 zero = {0.f, 0.f, 0.f, 0.f};
#pragma unroll
  for (int i = 0; i < 4; ++i)
#pragma unroll
    for (int j = 0; j < 4; ++j) acc[i][j] = zero;

  gemm_tile_768(X, W, m0, n0, ldsA, ldsB, acc);

  const int tid = threadIdx.x, lane = tid & 63, wave = tid >> 6;
  const int quad = lane >> 4, l16 = lane & 15;
  const int wm = wave >> 1, wn = wave & 1;

  const int which = bx / 6;                // 0=Q 1=K 2=V (uniform per block)
  const bool isV = (which == 2);
  // Q scale: 64^-0.5 * log2(e) folded (attn uses exp2)
  const float sc = (which == 0) ? 0.180336880f : 1.0f;
  u16* ep = lds;                           // 128x128 bf16 view

  __syncthreads();                         // K-loop LDS frag reads done
#pragma unroll
  for (int i = 0; i < 4; ++i)
#pragma unroll
    for (int j = 0; j < 4; ++j)
#pragma unroll
      for (int r = 0; r < 4; ++r) {
        const int m_l = wm * 64 + i * 16 + quad * 4 + r;   // token-local
        const int o_l = wn * 64 + j * 16 + l16;            // feat-local
        const int row = isV ? o_l : m_l;
        const int col = isV ? m_l : o_l;
        const int ch  = col >> 3;
        const int chs = (ch & 8) | ((ch & 7) ^ (row & 7));
        ep[row * 128 + chs * 8 + (col & 7)] = f2bf(acc[i][j][r] * sc);
      }
  __syncthreads();

  // coalesced store: thread -> (row, half); 8 x dwordx4 = 128B per thread
  const int row  = tid >> 1, half = tid & 1;
  const int b_   = m0 >> 10;               // batch (1024 % 128 == 0)
  const int nb   = m0 & 1023;              // token base within batch
  const int oc0  = n0 - which * 768;       // feat base within segment
  u16* dst;
  if (!isV) {
    const int h = (oc0 >> 6) + half;       // 2 heads per block
    dst = (which == 0 ? Qb : Kb) + (((size_t)(b_ * 12 + h)) * 1024 + nb + row) * 64;
  } else {
    const int h = (oc0 >> 6) + (row >> 6);
    const int d = row & 63;
    dst = Vt + (((size_t)(b_ * 12 + h)) * 64 + d) * 1024 + nb + half * 64;
  }
#pragma unroll
  for (int c = 0; c < 8; ++c) {
    const int chs = half * 8 + (c ^ (row & 7));
    *(u32x4*)(dst + c * 8) = *(const u32x4*)(ep + row * 128 + chs * 8);
  }
}

// Proj GEMM: M128 x N128 tiles -> grid (6,64) = 384 blocks = 8*48 -> chunked
// XCD swizzle. Same inner core as qkv (identical per-element K accumulation
// order -> identical numerics). Direct fp32 stores.
__global__ __launch_bounds__(256, 4) void proj_gemm_kernel(
    const u16* __restrict__ A, const u16* __restrict__ W,
    const float* __restrict__ bias, float* __restrict__ out)
{
  __shared__ alignas(16) u16 lds[2 * 128 * 64];    // 32 KB
  u16* ldsA = lds;
  u16* ldsB = lds + 128 * 64;

  const int id0 = blockIdx.y * 6 + blockIdx.x;
  const int swz = (id0 & 7) * 48 + (id0 >> 3);     // bijective (384%8==0)
  const int bx  = swz % 6, by = swz / 6;
  const int n0 = bx * 128;           // 0..640
  const int m0 = by * 128;           // 0..8064

  f32x4 acc[4][4];
  const f32x4 zero = {0.f, 0.f, 0.f, 0.f};
#pragma unroll
  for (int i = 0; i < 4; ++i)
#pragma unroll
    for (int j = 0; j < 4; ++j) acc[i][j] = zero;

  gemm_tile_768(A, W, m0, n0, ldsA, ldsB, acc);

  const int tid = threadIdx.x, lane = tid & 63, wave = tid >> 6;
  const int quad = lane >> 4, l16 = lane & 15;
  const int wm = wave >> 1, wn = wave & 1;

  float bv4[4];
#pragma unroll
  for (int j = 0; j < 4; ++j) bv4[j] = bias[n0 + wn * 64 + j * 16 + l16];

#pragma unroll
  for (int i = 0; i < 4; ++i)
#pragma unroll
    for (int j = 0; j < 4; ++j)
#pragma unroll
      for (int r = 0; r < 4; ++r) {
        const int m = m0 + wm * 64 + i * 16 + quad * 4 + r;
        out[(size_t)m * 768 + n0 + wn * 64 + j * 16 + l16] = acc[i][j][r] + bv4[j];
      }
}

// Attention v8: grid (96 heads, 8 q-blocks of 128), 256 threads = 4 waves,
// each wave 32 queries (2 strips of 16), full 1024-key sweep.
// 16 tiles of 64 keys, double-buffered gld_lds staging (zero VGPR cost):
//   per tile: vmcnt(0) -> s_barrier -> issue gld_lds(kt+1 -> other buf)
//             -> compute tile kt.
// The prefetch overlaps compute; the barrier (which every wave reaches only
// after finishing tile kt-1's LDS reads) makes the buffer swap WAR-safe.
// QK is computed TRANSPOSED (A=K-frag, B=Q-frag) so the C-layout hands each
// lane 4 consecutive keys of one P row -> packed b64 P-writes into wave-
// private pbuf; PV reads P rows as A-frags and Vt rows as B-frags.
// l-denominator: per-lane per-query(l16) scalar, quad-reduced in epilogue.
__global__ __launch_bounds__(256, 3) void attn_kernel(
    const u16* __restrict__ Q, const u16* __restrict__ K,
    const u16* __restrict__ Vt, __hip_bfloat16* __restrict__ O)
{
  __shared__ alignas(16) u16 ldsK[2 * 64 * 64];    // 16 KB: 2 bufs, keys x d
  __shared__ alignas(16) u16 ldsV[2 * 64 * 64];    // 16 KB: 2 bufs, d x keys
  __shared__ alignas(16) u16 pbuf[4 * 32 * 72];    // 18 KB: per-wave P slices
  const int bh = blockIdx.x;     // b*12 + h
  const int qb = blockIdx.y;     // 128-query block
  const int tid = threadIdx.x;
  const int wave = tid >> 6, lane = tid & 63;
  const int quad = lane >> 4, l16 = lane & 15;
  u16* pw = pbuf + wave * (32 * 72);

  const int q0 = qb * 128 + wave * 32;
  const u16* Kbh = K  + (size_t)bh * (1024 * 64);
  const u16* Vbh = Vt + (size_t)bh * (64 * 1024);

  // staging addresses: 2 issues each of K and V per 64-key tile
  // (2 x 256 x 16B = 8 KB per array per tile). Global addresses pre-swizzled;
  // LDS destination is the linear chunk (it*256+tid)*16B.
  const u16* gK[2]; const u16* gV[2]; int loK[2], loV[2];
#pragma unroll
  for (int it = 0; it < 2; ++it) {
    const int c = it * 256 + tid;          // 0..511
    {   // K tile: [key 0..63][8 chunks of 8 d-elems]
      const int row = c >> 3, cc = (c & 7) ^ (row & 7);
      gK[it] = Kbh + (size_t)row * 64 + cc * 8;
      loK[it] = (it * 256 + wave * 64) * 8;
    }
    {   // V tile: [d 0..63][8 chunks of 8 keys]
      const int row = c >> 3, cc = (c & 7) ^ (row & 7);
      gV[it] = Vbh + (size_t)row * 1024 + cc * 8;
      loV[it] = (it * 256 + wave * 64) * 8;
    }
  }

  // Q frags (B[n=q=l16][k=quad*8+j]), resident for the whole loop
  bf16x8 aQ0[2], aQ1[2];
#pragma unroll
  for (int s = 0; s < 2; ++s) {
    const u16* qp = Q + ((size_t)bh * 1024 + q0 + s * 16 + l16) * 64 + quad * 8;
    aQ0[s] = *(const bf16x8*)qp;
    aQ1[s] = *(const bf16x8*)(qp + 32);
  }

  f32x4 oacc[2][4];
  const f32x4 zero = {0.f, 0.f, 0.f, 0.f};
#pragma unroll
  for (int s = 0; s < 2; ++s)
#pragma unroll
    for (int db = 0; db < 4; ++db) oacc[s][db] = zero;
  float lacc[2] = {0.f, 0.f};    // per-lane denom partial for query (s, l16)

  // prologue: stage tile 0 into buffer 0
#pragma unroll
  for (int it = 0; it < 2; ++it) {
    gld_lds16(gK[it], ldsK + loK[it]);
    gld_lds16(gV[it], ldsV + loV[it]);
  }

#pragma unroll 2
  for (int kt = 0; kt < 16; ++kt) {       // 16 tiles of 64 keys
    const int cur = (kt & 1) * 4096;      // u16 offset of current buffer
    asm volatile("s_waitcnt vmcnt(0)" ::: "memory");   // buf[cur] landed
    __builtin_amdgcn_sched_barrier(0);
    __builtin_amdgcn_s_barrier();         // all staging visible + prev tile's
    __builtin_amdgcn_sched_barrier(0);    // LDS reads done (WAR for nxt buf)
    if (kt < 15) {                        // prefetch kt+1 under this compute
      const int nxt = ((kt + 1) & 1) * 4096;
#pragma unroll
      for (int it = 0; it < 2; ++it) {
        gld_lds16(gK[it] + (size_t)(kt + 1) * (64 * 64), ldsK + nxt + loK[it]);
        gld_lds16(gV[it] + (kt + 1) * 64, ldsV + nxt + loV[it]);
      }
    }

    // K frags (A[m=key=l16-in-group][k=quad*8+j]) from LDS, shared by waves
    bf16x8 kb0[4], kb1[4];
#pragma unroll
    for (int t = 0; t < 4; ++t) {
      const int row = t * 16 + l16;
      kb0[t] = *(const bf16x8*)(ldsK + cur + row * 64 + (((0 * 4 + quad) ^ (row & 7)) * 8));
      kb1[t] = *(const bf16x8*)(ldsK + cur + row * 64 + (((1 * 4 + quad) ^ (row & 7)) * 8));
    }
    asm volatile("" ::: "memory");  // WAR: prev tile's pa reads before stores
    // S^T = K Q^T (C: row=key quad*4+r, col=q l16); p = exp2;
    // packed b64 write into P[q][key] row (4 consecutive keys per lane)
#pragma unroll
    for (int s = 0; s < 2; ++s) {
#pragma unroll
      for (int t = 0; t < 4; ++t) {
        f32x4 z = zero;
        z = MFMA_BF16(kb0[t], aQ0[s], z);
        z = MFMA_BF16(kb1[t], aQ1[s], z);
        const float p0 = fast_exp2(z[0]);
        const float p1 = fast_exp2(z[1]);
        const float p2 = fast_exp2(z[2]);
        const float p3 = fast_exp2(z[3]);
        lacc[s] += (p0 + p1) + (p2 + p3);
        ushort4 pk;
        pk.x = f2bf(p0); pk.y = f2bf(p1); pk.z = f2bf(p2); pk.w = f2bf(p3);
        *(ushort4*)(pw + (s * 16 + l16) * 72 + t * 16 + quad * 4) = pk;
      }
    }
    asm volatile("" ::: "memory");  // RAW: P stores before reads (wave-priv)
    // P A-frags (A[m=q=l16][k=key=quad*8+j])
    bf16x8 pa0[2], pa1[2];
#pragma unroll
    for (int s = 0; s < 2; ++s) {
      const u16* pb = pw + (s * 16 + l16) * 72 + quad * 8;
      pa0[s] = *(const bf16x8*)pb;
      pa1[s] = *(const bf16x8*)(pb + 32);
    }
    // O += P V  (V frags from LDS as B[n=d=l16][k=key], reused across s)
#pragma unroll
    for (int db = 0; db < 4; ++db) {
      const int d = db * 16 + l16;
      const bf16x8 v0 = *(const bf16x8*)(ldsV + cur + d * 64 + (((0 * 4 + quad) ^ (d & 7))) * 8);
      const bf16x8 v1 = *(const bf16x8*)(ldsV + cur + d * 64 + (((1 * 4 + quad) ^ (d & 7))) * 8);
#pragma unroll
      for (int s = 0; s < 2; ++s) {
        oacc[s][db] = MFMA_BF16(pa0[s], v0, oacc[s][db]);
        oacc[s][db] = MFMA_BF16(pa1[s], v1, oacc[s][db]);
      }
    }
  }

  // epilogue: full denom per query (s,l16) = quad-reduce; broadcast to the
  // oacc row layout (row=q=quad*4+r, col=d=l16) via shfl, write O.
  const int b = bh / 12, h = bh - (bh / 12) * 12;
  float linv[2];
#pragma unroll
  for (int s = 0; s < 2; ++s) {
    float l = lacc[s];
    l += __shfl_xor(l, 16);
    l += __shfl_xor(l, 32);
    linv[s] = 1.f / l;        // uniform across quads; indexed by l16
  }
#pragma unroll
  for (int s = 0; s < 2; ++s) {
#pragma unroll
    for (int r = 0; r < 4; ++r) {
      const float inv = __shfl(linv[s], quad * 4 + r);   // denom of query row
      const int n = q0 + s * 16 + quad * 4 + r;
      __hip_bfloat16* orow = O + ((size_t)b * 1024 + n) * 768 + h * 64;
#pragma unroll
      for (int db = 0; db < 4; ++db)
        orow[db * 16 + l16] = __float2bfloat16(oacc[s][db][r] * inv);
    }
  }
}

extern "C" void kernel_launch(void* const* d_in, const int* in_sizes, int n_in,
                              void* d_out, int out_size, void* d_ws, size_t ws_size,
                              hipStream_t stream) {
  const float* x      = (const float*)d_in[0];   // [8,1024,768] fp32
  const float* w_qkv  = (const float*)d_in[1];   // [2304,768]  fp32
  const float* w_proj = (const float*)d_in[2];   // [768,768]   fp32
  const float* b_proj = (const float*)d_in[3];   // [768]       fp32
  float* out = (float*)d_out;                    // [8,1024,768] fp32

  char* ws = (char*)d_ws;
  const size_t SEG = (size_t)96 * 1024 * 64 * sizeof(u16);  // 12.58 MB
  u16* xb   = (u16*)(ws + 0 * SEG);              // x as bf16 [8192,768]
  u16* Qb   = (u16*)(ws + 1 * SEG);
  u16* Kb   = (u16*)(ws + 2 * SEG);
  u16* AO   = (u16*)(ws + 3 * SEG);              // attn out [8192,768] bf16
  u16* Vt   = (u16*)(ws + 4 * SEG);              // V^T [B,H,D,N]
  u16* wqb  = (u16*)(ws + 5 * SEG);              // w_qkv bf16 (3.54 MB)
  u16* wpb  = (u16*)(ws + 5 * SEG + 3538944);    // w_proj bf16 (1.18 MB)

  convert3_kernel<<<8448, 256, 0, stream>>>(x, xb, w_qkv, wqb, w_proj, wpb);
  qkv_gemm_kernel<<<dim3(18, 64), 256, 0, stream>>>(xb, wqb, Qb, Kb, Vt);
  attn_kernel    <<<dim3(96, 8), 256, 0, stream>>>(Qb, Kb, Vt, (__hip_bfloat16*)AO);
  proj_gemm_kernel<<<dim3(6, 64), 256, 0, stream>>>(AO, wpb, b_proj, out);
}